// Round 2
// baseline (320.625 us; speedup 1.0000x reference)
//
#include <hip/hip_runtime.h>
#include <hip/hip_bf16.h>

// Problem constants
#define BB 4
#define NN 512

// workspace layout (float offsets)
#define WS_V    0         // [B*N*32]
#define WS_HK   65536     // [B*N*64]  (k@aW1[:32] + ab1)
#define WS_HQ   196608    // [B*N*64]  (q@aW1[32:])
#define WS_AGG  327680    // [2(col)][2(jhalf)][B*N*32] = 262144 floats

// ---------------------------------------------------------------------------
// Kernel 1: k/q/v encoders (64->128->32) + hk/hq precompute, 8 rows per block
// ---------------------------------------------------------------------------
__global__ __launch_bounds__(128) void k_enc(
    const float* __restrict__ x,
    const float* __restrict__ kW1, const float* __restrict__ kb1,
    const float* __restrict__ kW2, const float* __restrict__ kb2,
    const float* __restrict__ qW1, const float* __restrict__ qb1,
    const float* __restrict__ qW2, const float* __restrict__ qb2,
    const float* __restrict__ vW1, const float* __restrict__ vb1,
    const float* __restrict__ vW2, const float* __restrict__ vb2,
    const float* __restrict__ aW1, const float* __restrict__ ab1,
    float* __restrict__ wsf)
{
  const int t = threadIdx.x;
  const int r0 = blockIdx.x * 8;          // global row base (b*N+n)
  __shared__ float xs[8][64];
  __shared__ float h1s[8][132];           // pad 132 to break bank conflicts
  __shared__ float encs[3][8][32];        // k,q,v outputs

  {                                        // 512 floats = 128 float4
    float4 f = ((const float4*)x)[(size_t)r0 * 16 + t];
    int m = t * 4;
    xs[m >> 6][m & 63] = f.x; xs[(m + 1) >> 6][(m + 1) & 63] = f.y;
    xs[(m + 2) >> 6][(m + 2) & 63] = f.z; xs[(m + 3) >> 6][(m + 3) & 63] = f.w;
  }
  __syncthreads();

  const int c = t & 31, rr = t >> 5;      // layer-2 mapping

  #pragma unroll
  for (int e = 0; e < 3; ++e) {
    const float* W1 = (e == 0) ? kW1 : (e == 1) ? qW1 : vW1;
    const float* b1 = (e == 0) ? kb1 : (e == 1) ? qb1 : vb1;
    const float* W2 = (e == 0) ? kW2 : (e == 1) ? qW2 : vW2;
    const float* b2 = (e == 0) ? kb2 : (e == 1) ? qb2 : vb2;

    // layer 1: 64 -> 128, thread t owns hidden unit t for all 8 rows
    float acc[8];
    {
      float bb = b1[t];
      #pragma unroll
      for (int r = 0; r < 8; ++r) acc[r] = bb;
    }
    for (int i = 0; i < 64; ++i) {
      float wv = W1[i * 128 + t];
      #pragma unroll
      for (int r = 0; r < 8; ++r) acc[r] = fmaf(xs[r][i], wv, acc[r]);
    }
    #pragma unroll
    for (int r = 0; r < 8; ++r) h1s[r][t] = fmaxf(acc[r], 0.f);
    __syncthreads();

    // layer 2: 128 -> 32, thread (rr,c) owns rows rr and rr+4, col c
    {
      float a0 = b2[c];
      float a1 = a0;
      for (int i = 0; i < 128; ++i) {
        float wv = W2[i * 32 + c];
        a0 = fmaf(h1s[rr][i], wv, a0);
        a1 = fmaf(h1s[rr + 4][i], wv, a1);
      }
      encs[e][rr][c] = a0;
      encs[e][rr + 4][c] = a1;
    }
    __syncthreads();
  }

  // store v (fp32)
  for (int m = t; m < 256; m += 128) wsf[WS_V + r0 * 32 + m] = encs[2][m >> 5][m & 31];

  // hk = k @ aW1[:32] + ab1 ; hq = q @ aW1[32:]   (thread: h = t&63, 4 rows)
  {
    const int h = t & 63, rr2 = t >> 6;   // rr2 in {0,1}: rows rr2*4 .. rr2*4+3
    float sk[4], sq[4];
    float ab1v = ab1[h];
    #pragma unroll
    for (int kk = 0; kk < 4; ++kk) { sk[kk] = ab1v; sq[kk] = 0.f; }
    for (int cc = 0; cc < 32; ++cc) {
      float wk = aW1[cc * 64 + h];
      float wq = aW1[(32 + cc) * 64 + h];
      #pragma unroll
      for (int kk = 0; kk < 4; ++kk) {
        sk[kk] = fmaf(encs[0][rr2 * 4 + kk][cc], wk, sk[kk]);
        sq[kk] = fmaf(encs[1][rr2 * 4 + kk][cc], wq, sq[kk]);
      }
    }
    #pragma unroll
    for (int kk = 0; kk < 4; ++kk) {
      wsf[WS_HK + (r0 + rr2 * 4 + kk) * 64 + h] = sk[kk];
      wsf[WS_HQ + (r0 + rr2 * 4 + kk) * 64 + h] = sq[kk];
    }
  }
}

// ---------------------------------------------------------------------------
// Kernel 2: attention scores + sigmoid gate + aggregation
// grid: b(4) x itile(64) x jhalf(2) = 512 blocks of 256 threads.
// phase1: t = c*128 + ii*16 + jj  -> score col c of pair (i0+ii, j0+jj)
// phase2: t = i2*32 + d2          -> agg[i0+i2][d2], both cols
// ---------------------------------------------------------------------------
__global__ __launch_bounds__(256) void k_att(
    const float* __restrict__ v_ws, const float* __restrict__ hk_ws,
    const float* __restrict__ hq_ws, const float* __restrict__ aW2,
    const float* __restrict__ ab2, float* __restrict__ aggh)
{
  const int t = threadIdx.x;
  const int bid = blockIdx.x;
  const int jh = bid & 1;
  const int it = (bid >> 1) & 63;
  const int b  = bid >> 7;
  const int i0 = it * 8;
  const int jbase = jh * 256;

  const int c  = t >> 7;
  const int ii = (t >> 4) & 7;
  const int jj = t & 15;
  const int ig = i0 + ii;

  const int i2 = t >> 5;
  const int d2 = t & 31;

  __shared__ float vs[16][32];
  __shared__ float ws_w[2][8][20];        // [col][ii][jj] padded rows

  // persistent registers: own score column of aW2, own hk row
  float aw2r[64];
  #pragma unroll
  for (int h = 0; h < 64; ++h) aw2r[h] = aW2[2 * h + c];
  const float sbias = ab2[c];

  float hk[64];
  {
    const float4* hkp = (const float4*)(hk_ws + ((size_t)b * NN + ig) * 64);
    #pragma unroll
    for (int m = 0; m < 16; ++m) {
      float4 f = hkp[m];
      hk[4 * m] = f.x; hk[4 * m + 1] = f.y; hk[4 * m + 2] = f.z; hk[4 * m + 3] = f.w;
    }
  }

  float acc0 = 0.f, acc1 = 0.f;

  for (int jt = 0; jt < 16; ++jt) {
    const int j0 = jbase + jt * 16;

    // hq row (register-only, safe before the barrier)
    float hq[64];
    {
      const float4* hqp = (const float4*)(hq_ws + ((size_t)b * NN + j0 + jj) * 64);
      #pragma unroll
      for (int m = 0; m < 16; ++m) {
        float4 f = hqp[m];
        hq[4 * m] = f.x; hq[4 * m + 1] = f.y; hq[4 * m + 2] = f.z; hq[4 * m + 3] = f.w;
      }
    }

    __syncthreads();   // previous phase2 finished reading vs / ws_w
    if (t < 128) {     // stage v tile: 16 rows x 32 d
      const int vr = t >> 3, vc = (t & 7) * 4;
      float4 f = *(const float4*)(v_ws + ((size_t)b * NN + j0 + vr) * 32 + vc);
      *(float4*)(&vs[vr][vc]) = f;
    }

    // phase 1: score col c for pair (ig, j0+jj)
    float s = sbias;
    #pragma unroll
    for (int h = 0; h < 64; ++h) {
      float z = fmaxf(hk[h] + hq[h], 0.f);
      s = fmaf(z, aw2r[h], s);
    }
    float w;
    if (ig == j0 + jj) {
      w = 0.f;                            // sigmoid(s - 10000) == 0 in fp32
    } else {
      w = 1.f / (1.f + __expf(-s));
    }
    ws_w[c][ii][jj] = w;
    __syncthreads();   // vs + w ready

    // phase 2: agg[i2, d2] += sum_j w[c][i2][j] * v[j][d2]
    #pragma unroll
    for (int jq = 0; jq < 4; ++jq) {
      float4 w0q = *(const float4*)(&ws_w[0][i2][jq * 4]);
      float4 w1q = *(const float4*)(&ws_w[1][i2][jq * 4]);
      float v0 = vs[jq * 4 + 0][d2], v1 = vs[jq * 4 + 1][d2];
      float v2 = vs[jq * 4 + 2][d2], v3 = vs[jq * 4 + 3][d2];
      acc0 = fmaf(w0q.x, v0, acc0); acc1 = fmaf(w1q.x, v0, acc1);
      acc0 = fmaf(w0q.y, v1, acc0); acc1 = fmaf(w1q.y, v1, acc1);
      acc0 = fmaf(w0q.z, v2, acc0); acc1 = fmaf(w1q.z, v2, acc1);
      acc0 = fmaf(w0q.w, v3, acc0); acc1 = fmaf(w1q.w, v3, acc1);
    }
  }

  const size_t row = (size_t)b * NN + i0 + i2;
  aggh[(size_t)jh * 65536 + row * 32 + d2] = acc0;                    // col0 partial
  aggh[131072 + (size_t)jh * 65536 + row * 32 + d2] = acc1;           // col1 partial
}

// ---------------------------------------------------------------------------
// Kernel 3: decoders (64->128->64) + mu/sig heads, 8 rows per block
// threads 0-127: x decoder, 128-255: y decoder
// ---------------------------------------------------------------------------
__global__ __launch_bounds__(256) void k_dec(
    const float* __restrict__ v_ws, const float* __restrict__ aggh,
    const float* __restrict__ dxW1, const float* __restrict__ dxb1,
    const float* __restrict__ dxW2, const float* __restrict__ dxb2,
    const float* __restrict__ dyW1, const float* __restrict__ dyb1,
    const float* __restrict__ dyW2, const float* __restrict__ dyb2,
    const float* __restrict__ mxW, const float* __restrict__ mxb,
    const float* __restrict__ sxW, const float* __restrict__ sxb,
    const float* __restrict__ myW, const float* __restrict__ myb,
    const float* __restrict__ syW, const float* __restrict__ syb,
    float* __restrict__ out)
{
  const int t = threadIdx.x;
  const int r0 = blockIdx.x * 8;
  const int half = t >> 7;                // 0: x-decoder (col0), 1: y-decoder (col1)
  const int u = t & 127;

  __shared__ float ccs[2][8][64];
  __shared__ float h1s[2][8][132];
  __shared__ float dds[2][8][64];

  {
    const float* aggp = aggh + (size_t)half * 131072;   // col half, both j-halves
    for (int m = u; m < 512; m += 128) {
      int r = m >> 6, i = m & 63;
      size_t row = (size_t)(r0 + r);
      float val = (i < 32) ? v_ws[row * 32 + i]
                           : (aggp[row * 32 + (i - 32)] + aggp[65536 + row * 32 + (i - 32)]);
      ccs[half][r][i] = val;
    }
  }
  __syncthreads();

  const float* W1 = half ? dyW1 : dxW1;
  const float* b1 = half ? dyb1 : dxb1;
  const float* W2 = half ? dyW2 : dxW2;
  const float* b2 = half ? dyb2 : dxb2;

  // layer 1: 64 -> 128
  {
    float acc[8];
    float bb = b1[u];
    #pragma unroll
    for (int r = 0; r < 8; ++r) acc[r] = bb;
    for (int i = 0; i < 64; ++i) {
      float wv = W1[i * 128 + u];
      #pragma unroll
      for (int r = 0; r < 8; ++r) acc[r] = fmaf(ccs[half][r][i], wv, acc[r]);
    }
    #pragma unroll
    for (int r = 0; r < 8; ++r) h1s[half][r][u] = fmaxf(acc[r], 0.f);
  }
  __syncthreads();

  // layer 2: 128 -> 64, thread (rr, cI) owns rows rr*4..rr*4+3
  {
    const int cI = u & 63, rr = u >> 6;
    float a4[4];
    float bb = b2[cI];
    #pragma unroll
    for (int kk = 0; kk < 4; ++kk) a4[kk] = bb;
    for (int i = 0; i < 128; ++i) {
      float wv = W2[i * 64 + cI];
      #pragma unroll
      for (int kk = 0; kk < 4; ++kk) a4[kk] = fmaf(h1s[half][rr * 4 + kk][i], wv, a4[kk]);
    }
    #pragma unroll
    for (int kk = 0; kk < 4; ++kk) dds[half][rr * 4 + kk][cI] = a4[kk];
  }
  __syncthreads();

  // heads: wave w handles 4 rows of one decoder half
  {
    const int w = t >> 6, halfw = w >> 1, rr = w & 1, lane = t & 63;
    const float* mW = halfw ? myW : mxW;
    const float* sW = halfw ? syW : sxW;
    const float* mb = halfw ? myb : mxb;
    const float* sb = halfw ? syb : sxb;
    float mwv = mW[lane], swv = sW[lane];
    #pragma unroll
    for (int kk = 0; kk < 4; ++kk) {
      int r = rr * 4 + kk;
      float dval = dds[halfw][r][lane];
      float pm = dval * mwv, ps = dval * swv;
      #pragma unroll
      for (int msk = 32; msk >= 1; msk >>= 1) {
        pm += __shfl_xor(pm, msk);
        ps += __shfl_xor(ps, msk);
      }
      if (lane == 0) {
        float mu = pm + mb[0];
        float z = ps + sb[0];
        float sp = (z > 20.f) ? z : log1pf(__expf(z));
        out[halfw * 4096 + (r0 + r)] = mu;            // mu
        out[halfw * 4096 + 2048 + (r0 + r)] = sp;     // sig
      }
    }
  }
}

// ---------------------------------------------------------------------------
extern "C" void kernel_launch(void* const* d_in, const int* in_sizes, int n_in,
                              void* d_out, int out_size, void* d_ws, size_t ws_size,
                              hipStream_t stream) {
  (void)in_sizes; (void)n_in; (void)out_size; (void)ws_size;
  const float* x   = (const float*)d_in[0];
  const float* kW1 = (const float*)d_in[1];  const float* kb1 = (const float*)d_in[2];
  const float* kW2 = (const float*)d_in[3];  const float* kb2 = (const float*)d_in[4];
  const float* qW1 = (const float*)d_in[5];  const float* qb1 = (const float*)d_in[6];
  const float* qW2 = (const float*)d_in[7];  const float* qb2 = (const float*)d_in[8];
  const float* vW1 = (const float*)d_in[9];  const float* vb1 = (const float*)d_in[10];
  const float* vW2 = (const float*)d_in[11]; const float* vb2 = (const float*)d_in[12];
  const float* aW1 = (const float*)d_in[13]; const float* ab1 = (const float*)d_in[14];
  const float* aW2 = (const float*)d_in[15]; const float* ab2 = (const float*)d_in[16];
  const float* dxW1 = (const float*)d_in[17]; const float* dxb1 = (const float*)d_in[18];
  const float* dxW2 = (const float*)d_in[19]; const float* dxb2 = (const float*)d_in[20];
  const float* dyW1 = (const float*)d_in[21]; const float* dyb1 = (const float*)d_in[22];
  const float* dyW2 = (const float*)d_in[23]; const float* dyb2 = (const float*)d_in[24];
  const float* mxW = (const float*)d_in[25]; const float* mxb = (const float*)d_in[26];
  const float* sxW = (const float*)d_in[27]; const float* sxb = (const float*)d_in[28];
  const float* myW = (const float*)d_in[29]; const float* myb = (const float*)d_in[30];
  const float* syW = (const float*)d_in[31]; const float* syb = (const float*)d_in[32];

  float* wsf = (float*)d_ws;
  float* out = (float*)d_out;

  hipLaunchKernelGGL(k_enc, dim3(256), dim3(128), 0, stream,
                     x, kW1, kb1, kW2, kb2, qW1, qb1, qW2, qb2, vW1, vb1, vW2, vb2,
                     aW1, ab1, wsf);
  hipLaunchKernelGGL(k_att, dim3(512), dim3(256), 0, stream,
                     wsf + WS_V, wsf + WS_HK, wsf + WS_HQ, aW2, ab2,
                     wsf + WS_AGG);
  hipLaunchKernelGGL(k_dec, dim3(256), dim3(256), 0, stream,
                     wsf + WS_V, wsf + WS_AGG,
                     dxW1, dxb1, dxW2, dxb2, dyW1, dyb1, dyW2, dyb2,
                     mxW, mxb, sxW, sxb, myW, myb, syW, syb, out);
}

// Round 5
// 234.105 us; speedup vs baseline: 1.3696x; 1.3696x over previous
//
#include <hip/hip_runtime.h>
#include <hip/hip_bf16.h>

// Problem constants
#define BB 4
#define NN 512
// total rows = B*N = 2048

// workspace layout (float offsets)
#define WS_V    0         // [2048*32]
#define WS_HK   65536     // [2048*64]  (k@aW1[:32] + ab1)
#define WS_HQ   196608    // [2048*64]  (q@aW1[32:])
#define WS_AGG  327680    // [2 col][4 jq][2048][32] = 524288 floats

// ---------------------------------------------------------------------------
// Kernel 1: k/q/v encoders (64->128->32) + hk/hq precompute
// 128 threads, 4 rows per block, 512 blocks
// ---------------------------------------------------------------------------
__global__ __launch_bounds__(128) void k_enc(
    const float* __restrict__ x,
    const float* __restrict__ kW1, const float* __restrict__ kb1,
    const float* __restrict__ kW2, const float* __restrict__ kb2,
    const float* __restrict__ qW1, const float* __restrict__ qb1,
    const float* __restrict__ qW2, const float* __restrict__ qb2,
    const float* __restrict__ vW1, const float* __restrict__ vb1,
    const float* __restrict__ vW2, const float* __restrict__ vb2,
    const float* __restrict__ aW1, const float* __restrict__ ab1,
    float* __restrict__ wsf)
{
  const int t = threadIdx.x;
  const int r0 = blockIdx.x * 4;          // global row base (b*N+n)
  __shared__ float xs[4][64];
  __shared__ float h1s[4][132];           // padded
  __shared__ float encs[3][4][32];        // k,q,v outputs

  if (t < 64) {                            // 256 floats = 64 float4
    float4 f = ((const float4*)x)[(size_t)r0 * 16 + t];
    int m = t * 4;
    xs[m >> 6][m & 63] = f.x; xs[(m + 1) >> 6][(m + 1) & 63] = f.y;
    xs[(m + 2) >> 6][(m + 2) & 63] = f.z; xs[(m + 3) >> 6][(m + 3) & 63] = f.w;
  }
  __syncthreads();

  #pragma unroll
  for (int e = 0; e < 3; ++e) {
    const float* W1 = (e == 0) ? kW1 : (e == 1) ? qW1 : vW1;
    const float* b1 = (e == 0) ? kb1 : (e == 1) ? qb1 : vb1;
    const float* W2 = (e == 0) ? kW2 : (e == 1) ? qW2 : vW2;
    const float* b2 = (e == 0) ? kb2 : (e == 1) ? qb2 : vb2;

    // layer 1: 64 -> 128, thread t owns hidden unit t for all 4 rows
    {
      float acc[4];
      float bb = b1[t];
      #pragma unroll
      for (int r = 0; r < 4; ++r) acc[r] = bb;
      #pragma unroll 4
      for (int i = 0; i < 64; ++i) {
        float wv = W1[i * 128 + t];
        #pragma unroll
        for (int r = 0; r < 4; ++r) acc[r] = fmaf(xs[r][i], wv, acc[r]);
      }
      #pragma unroll
      for (int r = 0; r < 4; ++r) h1s[r][t] = fmaxf(acc[r], 0.f);
    }
    __syncthreads();

    // layer 2: 128 -> 32, thread (rr,c): row rr, col c
    {
      const int c = t & 31, rr = t >> 5;
      float a0 = b2[c];
      #pragma unroll 4
      for (int i = 0; i < 128; ++i) {
        float wv = W2[i * 32 + c];
        a0 = fmaf(h1s[rr][i], wv, a0);
      }
      encs[e][rr][c] = a0;
    }
    __syncthreads();
  }

  // store v (fp32)
  {
    int r = t >> 5, cc = t & 31;
    wsf[WS_V + (r0 + r) * 32 + cc] = encs[2][r][cc];
  }

  // hk = k @ aW1[:32] + ab1 ; hq = q @ aW1[32:]
  // threads 0-63: sk (4 rows), 64-127: sq (4 rows)
  {
    const int h = t & 63, half = t >> 6;
    const int eidx = half;                 // 0 -> k (encs[0]), 1 -> q (encs[1])
    float s4[4];
    float bias = half ? 0.f : ab1[h];
    #pragma unroll
    for (int kk = 0; kk < 4; ++kk) s4[kk] = bias;
    const float* aw = aW1 + (half ? 32 * 64 : 0);
    #pragma unroll 4
    for (int cc = 0; cc < 32; ++cc) {
      float wv = aw[cc * 64 + h];
      #pragma unroll
      for (int kk = 0; kk < 4; ++kk)
        s4[kk] = fmaf(encs[eidx][kk][cc], wv, s4[kk]);
    }
    float* dst = wsf + (half ? WS_HQ : WS_HK);
    #pragma unroll
    for (int kk = 0; kk < 4; ++kk)
      dst[(size_t)(r0 + kk) * 64 + h] = s4[kk];
  }
}

// ---------------------------------------------------------------------------
// Kernel 2: attention scores + sigmoid gate + aggregation
// grid: b(4) x itile(64, 8 rows) x jquarter(4, 128 j's) = 1024 blocks x 256 thr
// phase1: t = c*128 + ii*16 + jj  -> score col c of pair (i0+ii, j0+jj)
// phase2: t = i2*32 + d2          -> agg[i0+i2][d2], both cols
// ---------------------------------------------------------------------------
__global__ __launch_bounds__(256) void k_att(
    const float* __restrict__ v_ws, const float* __restrict__ hk_ws,
    const float* __restrict__ hq_ws, const float* __restrict__ aW2,
    const float* __restrict__ ab2, float* __restrict__ aggh)
{
  const int t = threadIdx.x;
  const int bid = blockIdx.x;
  const int jq = bid & 3;
  const int it = (bid >> 2) & 63;
  const int b  = bid >> 8;
  const int i0 = it * 8;
  const int jbase = jq * 128;

  const int c  = t >> 7;
  const int ii = (t >> 4) & 7;
  const int jj = t & 15;
  const int ig = i0 + ii;

  const int i2 = t >> 5;
  const int d2 = t & 31;

  __shared__ float hqs[16][68];           // padded: 2-way conflicts only
  __shared__ float vs[16][36];
  __shared__ float ws_w[2][8][20];

  // persistent registers: own score column of aW2, own hk row
  float aw2r[64];
  {
    const float2* aw2p = (const float2*)aW2;
    #pragma unroll
    for (int h = 0; h < 64; ++h) {
      float2 p = aw2p[h];
      aw2r[h] = c ? p.y : p.x;
    }
  }
  const float sbias = ab2[c];

  float hk[64];
  {
    const float4* hkp = (const float4*)(hk_ws + ((size_t)b * NN + ig) * 64);
    #pragma unroll
    for (int m = 0; m < 16; ++m) {
      float4 f = hkp[m];
      hk[4 * m] = f.x; hk[4 * m + 1] = f.y; hk[4 * m + 2] = f.z; hk[4 * m + 3] = f.w;
    }
  }

  float acc0 = 0.f, acc1 = 0.f;

  for (int jt = 0; jt < 8; ++jt) {
    const int j0 = jbase + jt * 16;

    __syncthreads();   // previous phase2 finished reading vs / ws_w
    {                  // stage hq tile: 16 rows x 64 = 256 float4, one per thread
      const int hr = t >> 4, hc = (t & 15) * 4;
      float4 f = *(const float4*)(hq_ws + ((size_t)b * NN + j0 + hr) * 64 + hc);
      *(float4*)(&hqs[hr][hc]) = f;
    }
    if (t < 128) {     // stage v tile: 16 rows x 32
      const int vr = t >> 3, vc = (t & 7) * 4;
      float4 f = *(const float4*)(v_ws + ((size_t)b * NN + j0 + vr) * 32 + vc);
      *(float4*)(&vs[vr][vc]) = f;
    }
    __syncthreads();   // tiles ready

    // phase 1: score col c for pair (ig, j0+jj)
    {
      float s = sbias;
      #pragma unroll
      for (int m = 0; m < 16; ++m) {
        float4 hq4 = *(const float4*)(&hqs[jj][4 * m]);
        s = fmaf(fmaxf(hk[4 * m + 0] + hq4.x, 0.f), aw2r[4 * m + 0], s);
        s = fmaf(fmaxf(hk[4 * m + 1] + hq4.y, 0.f), aw2r[4 * m + 1], s);
        s = fmaf(fmaxf(hk[4 * m + 2] + hq4.z, 0.f), aw2r[4 * m + 2], s);
        s = fmaf(fmaxf(hk[4 * m + 3] + hq4.w, 0.f), aw2r[4 * m + 3], s);
      }
      float w;
      if (ig == j0 + jj) {
        w = 0.f;                          // sigmoid(s - 10000) == 0 in fp32
      } else {
        w = 1.f / (1.f + __expf(-s));
      }
      ws_w[c][ii][jj] = w;
    }
    __syncthreads();   // w ready

    // phase 2: agg[i2, d2] += sum_j w[c][i2][j] * v[j][d2]
    #pragma unroll
    for (int jb = 0; jb < 4; ++jb) {
      float4 w0q = *(const float4*)(&ws_w[0][i2][jb * 4]);
      float4 w1q = *(const float4*)(&ws_w[1][i2][jb * 4]);
      float v0 = vs[jb * 4 + 0][d2], v1 = vs[jb * 4 + 1][d2];
      float v2 = vs[jb * 4 + 2][d2], v3 = vs[jb * 4 + 3][d2];
      acc0 = fmaf(w0q.x, v0, acc0); acc1 = fmaf(w1q.x, v0, acc1);
      acc0 = fmaf(w0q.y, v1, acc0); acc1 = fmaf(w1q.y, v1, acc1);
      acc0 = fmaf(w0q.z, v2, acc0); acc1 = fmaf(w1q.z, v2, acc1);
      acc0 = fmaf(w0q.w, v3, acc0); acc1 = fmaf(w1q.w, v3, acc1);
    }
  }

  const size_t row = (size_t)b * NN + i0 + i2;
  aggh[((size_t)(0 * 4 + jq) * 2048 + row) * 32 + d2] = acc0;   // col0 partial
  aggh[((size_t)(1 * 4 + jq) * 2048 + row) * 32 + d2] = acc1;   // col1 partial
}

// ---------------------------------------------------------------------------
// Kernel 3: decoders (64->128->64) + mu/sig heads
// 256 threads, 4 rows per block, 512 blocks; threads 0-127 x-dec, 128-255 y-dec
// ---------------------------------------------------------------------------
__global__ __launch_bounds__(256) void k_dec(
    const float* __restrict__ v_ws, const float* __restrict__ aggh,
    const float* __restrict__ dxW1, const float* __restrict__ dxb1,
    const float* __restrict__ dxW2, const float* __restrict__ dxb2,
    const float* __restrict__ dyW1, const float* __restrict__ dyb1,
    const float* __restrict__ dyW2, const float* __restrict__ dyb2,
    const float* __restrict__ mxW, const float* __restrict__ mxb,
    const float* __restrict__ sxW, const float* __restrict__ sxb,
    const float* __restrict__ myW, const float* __restrict__ myb,
    const float* __restrict__ syW, const float* __restrict__ syb,
    float* __restrict__ out)
{
  const int t = threadIdx.x;
  const int r0 = blockIdx.x * 4;
  const int half = t >> 7;                // 0: x-decoder (col0), 1: y-decoder (col1)
  const int u = t & 127;

  __shared__ float ccs[2][4][64];
  __shared__ float h1s[2][4][132];
  __shared__ float dds[2][4][64];

  {
    const float* aggp = aggh + (size_t)half * 4 * 65536;   // col half, 4 jq partials
    for (int m = u; m < 256; m += 128) {
      int r = m >> 6, i = m & 63;
      size_t row = (size_t)(r0 + r);
      float val;
      if (i < 32) {
        val = v_ws[row * 32 + i];
      } else {
        int o = i - 32;
        val = aggp[row * 32 + o] + aggp[65536 + row * 32 + o]
            + aggp[131072 + row * 32 + o] + aggp[196608 + row * 32 + o];
      }
      ccs[half][r][i] = val;
    }
  }
  __syncthreads();

  const float* W1 = half ? dyW1 : dxW1;
  const float* b1 = half ? dyb1 : dxb1;
  const float* W2 = half ? dyW2 : dxW2;
  const float* b2 = half ? dyb2 : dxb2;

  // layer 1: 64 -> 128, thread u owns hidden unit u for 4 rows
  {
    float acc[4];
    float bb = b1[u];
    #pragma unroll
    for (int r = 0; r < 4; ++r) acc[r] = bb;
    #pragma unroll 4
    for (int i = 0; i < 64; ++i) {
      float wv = W1[i * 128 + u];
      #pragma unroll
      for (int r = 0; r < 4; ++r) acc[r] = fmaf(ccs[half][r][i], wv, acc[r]);
    }
    #pragma unroll
    for (int r = 0; r < 4; ++r) h1s[half][r][u] = fmaxf(acc[r], 0.f);
  }
  __syncthreads();

  // layer 2: 128 -> 64, thread (rr, cI) owns rows rr*2, rr*2+1
  {
    const int cI = u & 63, rr = u >> 6;
    float a0 = b2[cI], a1 = a0;
    #pragma unroll 4
    for (int i = 0; i < 128; ++i) {
      float wv = W2[i * 64 + cI];
      a0 = fmaf(h1s[half][rr * 2 + 0][i], wv, a0);
      a1 = fmaf(h1s[half][rr * 2 + 1][i], wv, a1);
    }
    dds[half][rr * 2 + 0][cI] = a0;
    dds[half][rr * 2 + 1][cI] = a1;
  }
  __syncthreads();

  // heads: wave w handles 2 rows of one decoder half
  {
    const int w = t >> 6, halfw = w >> 1, rr = w & 1, lane = t & 63;
    const float* mW = halfw ? myW : mxW;
    const float* sW = halfw ? syW : sxW;
    const float* mb = halfw ? myb : mxb;
    const float* sb = halfw ? syb : sxb;
    float mwv = mW[lane], swv = sW[lane];
    #pragma unroll
    for (int kk = 0; kk < 2; ++kk) {
      int r = rr * 2 + kk;
      float dval = dds[halfw][r][lane];
      float pm = dval * mwv, ps = dval * swv;
      #pragma unroll
      for (int msk = 32; msk >= 1; msk >>= 1) {
        pm += __shfl_xor(pm, msk);
        ps += __shfl_xor(ps, msk);
      }
      if (lane == 0) {
        float mu = pm + mb[0];
        float z = ps + sb[0];
        float sp = (z > 20.f) ? z : log1pf(__expf(z));
        out[halfw * 4096 + (r0 + r)] = mu;            // mu
        out[halfw * 4096 + 2048 + (r0 + r)] = sp;     // sig
      }
    }
  }
}

// ---------------------------------------------------------------------------
extern "C" void kernel_launch(void* const* d_in, const int* in_sizes, int n_in,
                              void* d_out, int out_size, void* d_ws, size_t ws_size,
                              hipStream_t stream) {
  (void)in_sizes; (void)n_in; (void)out_size; (void)ws_size;
  const float* x   = (const float*)d_in[0];
  const float* kW1 = (const float*)d_in[1];  const float* kb1 = (const float*)d_in[2];
  const float* kW2 = (const float*)d_in[3];  const float* kb2 = (const float*)d_in[4];
  const float* qW1 = (const float*)d_in[5];  const float* qb1 = (const float*)d_in[6];
  const float* qW2 = (const float*)d_in[7];  const float* qb2 = (const float*)d_in[8];
  const float* vW1 = (const float*)d_in[9];  const float* vb1 = (const float*)d_in[10];
  const float* vW2 = (const float*)d_in[11]; const float* vb2 = (const float*)d_in[12];
  const float* aW1 = (const float*)d_in[13]; const float* ab1 = (const float*)d_in[14];
  const float* aW2 = (const float*)d_in[15]; const float* ab2 = (const float*)d_in[16];
  const float* dxW1 = (const float*)d_in[17]; const float* dxb1 = (const float*)d_in[18];
  const float* dxW2 = (const float*)d_in[19]; const float* dxb2 = (const float*)d_in[20];
  const float* dyW1 = (const float*)d_in[21]; const float* dyb1 = (const float*)d_in[22];
  const float* dyW2 = (const float*)d_in[23]; const float* dyb2 = (const float*)d_in[24];
  const float* mxW = (const float*)d_in[25]; const float* mxb = (const float*)d_in[26];
  const float* sxW = (const float*)d_in[27]; const float* sxb = (const float*)d_in[28];
  const float* myW = (const float*)d_in[29]; const float* myb = (const float*)d_in[30];
  const float* syW = (const float*)d_in[31]; const float* syb = (const float*)d_in[32];

  float* wsf = (float*)d_ws;
  float* out = (float*)d_out;

  hipLaunchKernelGGL(k_enc, dim3(512), dim3(128), 0, stream,
                     x, kW1, kb1, kW2, kb2, qW1, qb1, qW2, qb2, vW1, vb1, vW2, vb2,
                     aW1, ab1, wsf);
  hipLaunchKernelGGL(k_att, dim3(1024), dim3(256), 0, stream,
                     wsf + WS_V, wsf + WS_HK, wsf + WS_HQ, aW2, ab2,
                     wsf + WS_AGG);
  hipLaunchKernelGGL(k_dec, dim3(512), dim3(256), 0, stream,
                     wsf + WS_V, wsf + WS_AGG,
                     dxW1, dxb1, dxW2, dxb2, dyW1, dyb1, dyW2, dyb2,
                     mxW, mxb, sxW, sxb, myW, myb, syW, syb, out);
}

// Round 7
// 203.236 us; speedup vs baseline: 1.5776x; 1.1519x over previous
//
#include <hip/hip_runtime.h>
#include <hip/hip_bf16.h>

// Problem constants
#define BB 4
#define NN 512
// total rows = B*N = 2048

// workspace layout (float offsets)
#define WS_V    0         // [2048*32]
#define WS_HK   65536     // [2048*64]  (k@aW1[:32] + ab1)
#define WS_HQ   196608    // [2048*64]  (q@aW1[32:])
#define WS_AGG  327680    // [2 col][4 jq][2048][32] = 524288 floats

// ---------------------------------------------------------------------------
// Kernel 1: k/q/v encoders (64->128->32) + hk/hq precompute  (unchanged)
// ---------------------------------------------------------------------------
__global__ __launch_bounds__(128) void k_enc(
    const float* __restrict__ x,
    const float* __restrict__ kW1, const float* __restrict__ kb1,
    const float* __restrict__ kW2, const float* __restrict__ kb2,
    const float* __restrict__ qW1, const float* __restrict__ qb1,
    const float* __restrict__ qW2, const float* __restrict__ qb2,
    const float* __restrict__ vW1, const float* __restrict__ vb1,
    const float* __restrict__ vW2, const float* __restrict__ vb2,
    const float* __restrict__ aW1, const float* __restrict__ ab1,
    float* __restrict__ wsf)
{
  const int t = threadIdx.x;
  const int r0 = blockIdx.x * 4;          // global row base (b*N+n)
  __shared__ float xs[4][64];
  __shared__ float h1s[4][132];           // padded
  __shared__ float encs[3][4][32];        // k,q,v outputs

  if (t < 64) {                            // 256 floats = 64 float4
    float4 f = ((const float4*)x)[(size_t)r0 * 16 + t];
    int m = t * 4;
    xs[m >> 6][m & 63] = f.x; xs[(m + 1) >> 6][(m + 1) & 63] = f.y;
    xs[(m + 2) >> 6][(m + 2) & 63] = f.z; xs[(m + 3) >> 6][(m + 3) & 63] = f.w;
  }
  __syncthreads();

  #pragma unroll
  for (int e = 0; e < 3; ++e) {
    const float* W1 = (e == 0) ? kW1 : (e == 1) ? qW1 : vW1;
    const float* b1 = (e == 0) ? kb1 : (e == 1) ? qb1 : vb1;
    const float* W2 = (e == 0) ? kW2 : (e == 1) ? qW2 : vW2;
    const float* b2 = (e == 0) ? kb2 : (e == 1) ? qb2 : vb2;

    // layer 1: 64 -> 128, thread t owns hidden unit t for all 4 rows
    {
      float acc[4];
      float bb = b1[t];
      #pragma unroll
      for (int r = 0; r < 4; ++r) acc[r] = bb;
      #pragma unroll 4
      for (int i = 0; i < 64; ++i) {
        float wv = W1[i * 128 + t];
        #pragma unroll
        for (int r = 0; r < 4; ++r) acc[r] = fmaf(xs[r][i], wv, acc[r]);
      }
      #pragma unroll
      for (int r = 0; r < 4; ++r) h1s[r][t] = fmaxf(acc[r], 0.f);
    }
    __syncthreads();

    // layer 2: 128 -> 32, thread (rr,c): row rr, col c
    {
      const int c = t & 31, rr = t >> 5;
      float a0 = b2[c];
      #pragma unroll 4
      for (int i = 0; i < 128; ++i) {
        float wv = W2[i * 32 + c];
        a0 = fmaf(h1s[rr][i], wv, a0);
      }
      encs[e][rr][c] = a0;
    }
    __syncthreads();
  }

  // store v (fp32)
  {
    int r = t >> 5, cc = t & 31;
    wsf[WS_V + (r0 + r) * 32 + cc] = encs[2][r][cc];
  }

  // hk = k @ aW1[:32] + ab1 ; hq = q @ aW1[32:]
  // threads 0-63: sk (4 rows), 64-127: sq (4 rows)
  {
    const int h = t & 63, half = t >> 6;
    const int eidx = half;                 // 0 -> k (encs[0]), 1 -> q (encs[1])
    float s4[4];
    float bias = half ? 0.f : ab1[h];
    #pragma unroll
    for (int kk = 0; kk < 4; ++kk) s4[kk] = bias;
    const float* aw = aW1 + (half ? 32 * 64 : 0);
    #pragma unroll 4
    for (int cc = 0; cc < 32; ++cc) {
      float wv = aw[cc * 64 + h];
      #pragma unroll
      for (int kk = 0; kk < 4; ++kk)
        s4[kk] = fmaf(encs[eidx][kk][cc], wv, s4[kk]);
    }
    float* dst = wsf + (half ? WS_HQ : WS_HK);
    #pragma unroll
    for (int kk = 0; kk < 4; ++kk)
      dst[(size_t)(r0 + kk) * 64 + h] = s4[kk];
  }
}

// ---------------------------------------------------------------------------
// Kernel 2: attention scores + sigmoid gate + aggregation  (v3: h-split)
// grid: b(4) x itile(128, 4 rows) x jquarter(4, 128 j's) = 2048 blocks x 256 thr
// phase1: t = ii*64 + jj*4 + q  -> lane-quarter q owns h in [q*16, q*16+16)
//         computes partial s0,s1 for pair (i0+ii, j0+jj); shfl-combine over q.
// phase2: t = i2*64 + jh*32 + c2*16 + dd -> agg[i0+i2][2dd..2dd+1], col c2,
//         j-half jh; shfl-combine over jh.
// Double-buffered hq/v LDS tiles; 2 barriers per 16-j tile; next-tile global
// loads issued at phase1-top (latency hidden under compute).
// ---------------------------------------------------------------------------
__global__ __launch_bounds__(256, 4) void k_att(
    const float* __restrict__ v_ws, const float* __restrict__ hk_ws,
    const float* __restrict__ hq_ws, const float* __restrict__ aW2,
    const float* __restrict__ ab2, float* __restrict__ aggh)
{
  const int t = threadIdx.x;
  const int bid = blockIdx.x;
  const int jq = bid & 3;
  const int it = (bid >> 2) & 127;
  const int b  = bid >> 9;
  const int i0 = it * 4;
  const int jbase = jq * 128;

  // phase1 identity
  const int q   = t & 3;
  const int jj1 = (t >> 2) & 15;
  const int ii1 = t >> 6;
  const int ig  = i0 + ii1;

  // phase2 identity
  const int dd  = t & 15;
  const int c2  = (t >> 4) & 1;
  const int jh  = (t >> 5) & 1;
  const int i2  = t >> 6;

  __shared__ float hqs[2][16][68];
  __shared__ float vs[2][16][36];
  __shared__ float ws_w[2][4][20];        // [col][ii][jj]

  // persistent registers: 16 hk values + 16 aw2 per col for this lane-quarter
  float hk16[16];
  {
    const float4* hkp = (const float4*)(hk_ws + ((size_t)b * NN + ig) * 64 + q * 16);
    #pragma unroll
    for (int m = 0; m < 4; ++m) {
      float4 f = hkp[m];
      hk16[4 * m] = f.x; hk16[4 * m + 1] = f.y;
      hk16[4 * m + 2] = f.z; hk16[4 * m + 3] = f.w;
    }
  }
  float aw0[16], aw1[16];
  {
    const float4* awp = (const float4*)(aW2 + q * 32);  // pairs (h,c0),(h,c1)
    #pragma unroll
    for (int k = 0; k < 8; ++k) {
      float4 f = awp[k];
      aw0[2 * k] = f.x;     aw1[2 * k] = f.y;
      aw0[2 * k + 1] = f.z; aw1[2 * k + 1] = f.w;
    }
  }
  const float sb0 = ab2[0], sb1 = ab2[1];

  float accx = 0.f, accy = 0.f;
  const bool vload = (t < 128);

  // prologue: stage tile 0 into buffer 0
  {
    float4 hq_r = *(const float4*)(hq_ws + ((size_t)b * NN + jbase + (t >> 4)) * 64 + (t & 15) * 4);
    *(float4*)(&hqs[0][t >> 4][(t & 15) * 4]) = hq_r;
    if (vload) {
      float4 v_r = *(const float4*)(v_ws + ((size_t)b * NN + jbase + (t >> 3)) * 32 + (t & 7) * 4);
      *(float4*)(&vs[0][t >> 3][(t & 7) * 4]) = v_r;
    }
  }
  __syncthreads();

  int p = 0;
  for (int jt = 0; jt < 8; ++jt) {
    const int j0 = jbase + jt * 16;

    // issue next-tile global loads early (hidden under phase1 compute)
    float4 hq_n, v_n;
    if (jt < 7) {
      const int j0n = j0 + 16;
      hq_n = *(const float4*)(hq_ws + ((size_t)b * NN + j0n + (t >> 4)) * 64 + (t & 15) * 4);
      if (vload)
        v_n = *(const float4*)(v_ws + ((size_t)b * NN + j0n + (t >> 3)) * 32 + (t & 7) * 4);
    }

    // phase 1: partial scores over this lane's 16 h's, both cols
    {
      float s0 = 0.f, s1 = 0.f;
      #pragma unroll
      for (int mc = 0; mc < 4; ++mc) {
        float4 hq4 = *(const float4*)(&hqs[p][jj1][q * 16 + mc * 4]);
        float z;
        z = fmaxf(hk16[4 * mc + 0] + hq4.x, 0.f);
        s0 = fmaf(z, aw0[4 * mc + 0], s0); s1 = fmaf(z, aw1[4 * mc + 0], s1);
        z = fmaxf(hk16[4 * mc + 1] + hq4.y, 0.f);
        s0 = fmaf(z, aw0[4 * mc + 1], s0); s1 = fmaf(z, aw1[4 * mc + 1], s1);
        z = fmaxf(hk16[4 * mc + 2] + hq4.z, 0.f);
        s0 = fmaf(z, aw0[4 * mc + 2], s0); s1 = fmaf(z, aw1[4 * mc + 2], s1);
        z = fmaxf(hk16[4 * mc + 3] + hq4.w, 0.f);
        s0 = fmaf(z, aw0[4 * mc + 3], s0); s1 = fmaf(z, aw1[4 * mc + 3], s1);
      }
      // combine the 4 lane-quarters (bits 0-1 of t)
      s0 += __shfl_xor(s0, 1); s0 += __shfl_xor(s0, 2);
      s1 += __shfl_xor(s1, 1); s1 += __shfl_xor(s1, 2);
      s0 += sb0; s1 += sb1;
      // lanes q0/q2 produce col0, q1/q3 col1; q0,q1 write
      float sel = (q & 1) ? s1 : s0;
      float w = 1.f / (1.f + __expf(-sel));
      if (ig == j0 + jj1) w = 0.f;        // sigmoid(s - 10000) == 0 in fp32
      if (q < 2) ws_w[q][ii1][jj1] = w;
    }
    __syncthreads();   // w ready; vs[p] already ready

    // phase 2: agg partial for (i2, d=2dd..2dd+1, col c2, j-half jh)
    {
      float4 w4a = *(const float4*)(&ws_w[c2][i2][jh * 8]);
      float4 w4b = *(const float4*)(&ws_w[c2][i2][jh * 8 + 4]);
      const int jb = jh * 8;
      float2 vv;
      vv = *(const float2*)(&vs[p][jb + 0][2 * dd]);
      accx = fmaf(w4a.x, vv.x, accx); accy = fmaf(w4a.x, vv.y, accy);
      vv = *(const float2*)(&vs[p][jb + 1][2 * dd]);
      accx = fmaf(w4a.y, vv.x, accx); accy = fmaf(w4a.y, vv.y, accy);
      vv = *(const float2*)(&vs[p][jb + 2][2 * dd]);
      accx = fmaf(w4a.z, vv.x, accx); accy = fmaf(w4a.z, vv.y, accy);
      vv = *(const float2*)(&vs[p][jb + 3][2 * dd]);
      accx = fmaf(w4a.w, vv.x, accx); accy = fmaf(w4a.w, vv.y, accy);
      vv = *(const float2*)(&vs[p][jb + 4][2 * dd]);
      accx = fmaf(w4b.x, vv.x, accx); accy = fmaf(w4b.x, vv.y, accy);
      vv = *(const float2*)(&vs[p][jb + 5][2 * dd]);
      accx = fmaf(w4b.y, vv.x, accx); accy = fmaf(w4b.y, vv.y, accy);
      vv = *(const float2*)(&vs[p][jb + 6][2 * dd]);
      accx = fmaf(w4b.z, vv.x, accx); accy = fmaf(w4b.z, vv.y, accy);
      vv = *(const float2*)(&vs[p][jb + 7][2 * dd]);
      accx = fmaf(w4b.w, vv.x, accx); accy = fmaf(w4b.w, vv.y, accy);
    }

    // stage next tile into the other buffer (no conflict with phase2 reads)
    if (jt < 7) {
      *(float4*)(&hqs[p ^ 1][t >> 4][(t & 15) * 4]) = hq_n;
      if (vload) *(float4*)(&vs[p ^ 1][t >> 3][(t & 7) * 4]) = v_n;
    }
    __syncthreads();   // next buffer staged; ws_w free for next phase1
    p ^= 1;
  }

  // combine j-halves (bit 5 of t) and store
  accx += __shfl_xor(accx, 32);
  accy += __shfl_xor(accy, 32);
  if (jh == 0) {
    const size_t row = (size_t)b * NN + i0 + i2;
    float2 o; o.x = accx; o.y = accy;
    *(float2*)(&aggh[((size_t)(c2 * 4 + jq) * 2048 + row) * 32 + 2 * dd]) = o;
  }
}

// ---------------------------------------------------------------------------
// Kernel 3: decoders (64->128->64) + mu/sig heads  (unchanged)
// ---------------------------------------------------------------------------
__global__ __launch_bounds__(256) void k_dec(
    const float* __restrict__ v_ws, const float* __restrict__ aggh,
    const float* __restrict__ dxW1, const float* __restrict__ dxb1,
    const float* __restrict__ dxW2, const float* __restrict__ dxb2,
    const float* __restrict__ dyW1, const float* __restrict__ dyb1,
    const float* __restrict__ dyW2, const float* __restrict__ dyb2,
    const float* __restrict__ mxW, const float* __restrict__ mxb,
    const float* __restrict__ sxW, const float* __restrict__ sxb,
    const float* __restrict__ myW, const float* __restrict__ myb,
    const float* __restrict__ syW, const float* __restrict__ syb,
    float* __restrict__ out)
{
  const int t = threadIdx.x;
  const int r0 = blockIdx.x * 4;
  const int half = t >> 7;                // 0: x-decoder (col0), 1: y-decoder (col1)
  const int u = t & 127;

  __shared__ float ccs[2][4][64];
  __shared__ float h1s[2][4][132];
  __shared__ float dds[2][4][64];

  {
    const float* aggp = aggh + (size_t)half * 4 * 65536;   // col half, 4 jq partials
    for (int m = u; m < 256; m += 128) {
      int r = m >> 6, i = m & 63;
      size_t row = (size_t)(r0 + r);
      float val;
      if (i < 32) {
        val = v_ws[row * 32 + i];
      } else {
        int o = i - 32;
        val = aggp[row * 32 + o] + aggp[65536 + row * 32 + o]
            + aggp[131072 + row * 32 + o] + aggp[196608 + row * 32 + o];
      }
      ccs[half][r][i] = val;
    }
  }
  __syncthreads();

  const float* W1 = half ? dyW1 : dxW1;
  const float* b1 = half ? dyb1 : dxb1;
  const float* W2 = half ? dyW2 : dxW2;
  const float* b2 = half ? dyb2 : dxb2;

  // layer 1: 64 -> 128, thread u owns hidden unit u for 4 rows
  {
    float acc[4];
    float bb = b1[u];
    #pragma unroll
    for (int r = 0; r < 4; ++r) acc[r] = bb;
    #pragma unroll 4
    for (int i = 0; i < 64; ++i) {
      float wv = W1[i * 128 + u];
      #pragma unroll
      for (int r = 0; r < 4; ++r) acc[r] = fmaf(ccs[half][r][i], wv, acc[r]);
    }
    #pragma unroll
    for (int r = 0; r < 4; ++r) h1s[half][r][u] = fmaxf(acc[r], 0.f);
  }
  __syncthreads();

  // layer 2: 128 -> 64, thread (rr, cI) owns rows rr*2, rr*2+1
  {
    const int cI = u & 63, rr = u >> 6;
    float a0 = b2[cI], a1 = a0;
    #pragma unroll 4
    for (int i = 0; i < 128; ++i) {
      float wv = W2[i * 64 + cI];
      a0 = fmaf(h1s[half][rr * 2 + 0][i], wv, a0);
      a1 = fmaf(h1s[half][rr * 2 + 1][i], wv, a1);
    }
    dds[half][rr * 2 + 0][cI] = a0;
    dds[half][rr * 2 + 1][cI] = a1;
  }
  __syncthreads();

  // heads: wave w handles 2 rows of one decoder half
  {
    const int w = t >> 6, halfw = w >> 1, rr = w & 1, lane = t & 63;
    const float* mW = halfw ? myW : mxW;
    const float* sW = halfw ? syW : sxW;
    const float* mb = halfw ? myb : mxb;
    const float* sb = halfw ? syb : sxb;
    float mwv = mW[lane], swv = sW[lane];
    #pragma unroll
    for (int kk = 0; kk < 2; ++kk) {
      int r = rr * 2 + kk;
      float dval = dds[halfw][r][lane];
      float pm = dval * mwv, ps = dval * swv;
      #pragma unroll
      for (int msk = 32; msk >= 1; msk >>= 1) {
        pm += __shfl_xor(pm, msk);
        ps += __shfl_xor(ps, msk);
      }
      if (lane == 0) {
        float mu = pm + mb[0];
        float z = ps + sb[0];
        float sp = (z > 20.f) ? z : log1pf(__expf(z));
        out[halfw * 4096 + (r0 + r)] = mu;            // mu
        out[halfw * 4096 + 2048 + (r0 + r)] = sp;     // sig
      }
    }
  }
}

// ---------------------------------------------------------------------------
extern "C" void kernel_launch(void* const* d_in, const int* in_sizes, int n_in,
                              void* d_out, int out_size, void* d_ws, size_t ws_size,
                              hipStream_t stream) {
  (void)in_sizes; (void)n_in; (void)out_size; (void)ws_size;
  const float* x   = (const float*)d_in[0];
  const float* kW1 = (const float*)d_in[1];  const float* kb1 = (const float*)d_in[2];
  const float* kW2 = (const float*)d_in[3];  const float* kb2 = (const float*)d_in[4];
  const float* qW1 = (const float*)d_in[5];  const float* qb1 = (const float*)d_in[6];
  const float* qW2 = (const float*)d_in[7];  const float* qb2 = (const float*)d_in[8];
  const float* vW1 = (const float*)d_in[9];  const float* vb1 = (const float*)d_in[10];
  const float* vW2 = (const float*)d_in[11]; const float* vb2 = (const float*)d_in[12];
  const float* aW1 = (const float*)d_in[13]; const float* ab1 = (const float*)d_in[14];
  const float* aW2 = (const float*)d_in[15]; const float* ab2 = (const float*)d_in[16];
  const float* dxW1 = (const float*)d_in[17]; const float* dxb1 = (const float*)d_in[18];
  const float* dxW2 = (const float*)d_in[19]; const float* dxb2 = (const float*)d_in[20];
  const float* dyW1 = (const float*)d_in[21]; const float* dyb1 = (const float*)d_in[22];
  const float* dyW2 = (const float*)d_in[23]; const float* dyb2 = (const float*)d_in[24];
  const float* mxW = (const float*)d_in[25]; const float* mxb = (const float*)d_in[26];
  const float* sxW = (const float*)d_in[27]; const float* sxb = (const float*)d_in[28];
  const float* myW = (const float*)d_in[29]; const float* myb = (const float*)d_in[30];
  const float* syW = (const float*)d_in[31]; const float* syb = (const float*)d_in[32];

  float* wsf = (float*)d_ws;
  float* out = (float*)d_out;

  hipLaunchKernelGGL(k_enc, dim3(512), dim3(128), 0, stream,
                     x, kW1, kb1, kW2, kb2, qW1, qb1, qW2, qb2, vW1, vb1, vW2, vb2,
                     aW1, ab1, wsf);
  hipLaunchKernelGGL(k_att, dim3(2048), dim3(256), 0, stream,
                     wsf + WS_V, wsf + WS_HK, wsf + WS_HQ, aW2, ab2,
                     wsf + WS_AGG);
  hipLaunchKernelGGL(k_dec, dim3(512), dim3(256), 0, stream,
                     wsf + WS_V, wsf + WS_AGG,
                     dxW1, dxb1, dxW2, dxb2, dyW1, dyb1, dyW2, dyb2,
                     mxW, mxb, sxW, sxb, myW, myb, syW, syb, out);
}

// Round 10
// 174.958 us; speedup vs baseline: 1.8326x; 1.1616x over previous
//
#include <hip/hip_runtime.h>
#include <hip/hip_bf16.h>

// Problem constants
#define BB 4
#define NN 512
// total rows = B*N = 2048

// workspace layout (float offsets)
#define WS_V    0         // [2048*32]
#define WS_HK   65536     // [2048*64]  (k@aW1[:32] + ab1)
#define WS_HQ   196608    // [2048*64]  (q@aW1[32:])
#define WS_AGG  327680    // [2 col][4 jq][2048][32] = 524288 floats

// ---------------------------------------------------------------------------
// Kernel 1 (v2): one encoder per block. grid = e(3) x rowtile(256, 8 rows),
// 256 threads. hk folded into e==0 blocks, hq into e==1 blocks.
// ---------------------------------------------------------------------------
__global__ __launch_bounds__(256) void k_enc(
    const float* __restrict__ x,
    const float* __restrict__ kW1, const float* __restrict__ kb1,
    const float* __restrict__ kW2, const float* __restrict__ kb2,
    const float* __restrict__ qW1, const float* __restrict__ qb1,
    const float* __restrict__ qW2, const float* __restrict__ qb2,
    const float* __restrict__ vW1, const float* __restrict__ vb1,
    const float* __restrict__ vW2, const float* __restrict__ vb2,
    const float* __restrict__ aW1, const float* __restrict__ ab1,
    float* __restrict__ wsf)
{
  const int t = threadIdx.x;
  const int bid = blockIdx.x;
  const int e  = bid >> 8;                // 0=k, 1=q, 2=v
  const int r0 = (bid & 255) * 8;         // global row base

  __shared__ float xs[8][64];
  __shared__ float h1s[8][132];           // padded
  __shared__ float encs[8][33];           // this encoder's 8x32 output

  const float* W1 = (e == 0) ? kW1 : (e == 1) ? qW1 : vW1;
  const float* b1 = (e == 0) ? kb1 : (e == 1) ? qb1 : vb1;
  const float* W2 = (e == 0) ? kW2 : (e == 1) ? qW2 : vW2;
  const float* b2 = (e == 0) ? kb2 : (e == 1) ? qb2 : vb2;

  {                                        // stage x: 512 floats, float2 each
    float2 f = ((const float2*)x)[(size_t)r0 * 32 + t];
    int m = t * 2;
    xs[m >> 6][m & 63] = f.x;
    xs[(m + 1) >> 6][(m + 1) & 63] = f.y;
  }
  __syncthreads();

  // layer 1: 64 -> 128. thread (h = t&127, rh = t>>7): 4 rows each
  {
    const int h = t & 127, rh = t >> 7;
    float acc[4];
    float bb = b1[h];
    #pragma unroll
    for (int r = 0; r < 4; ++r) acc[r] = bb;
    #pragma unroll 4
    for (int i = 0; i < 64; ++i) {
      float wv = W1[i * 128 + h];
      #pragma unroll
      for (int r = 0; r < 4; ++r) acc[r] = fmaf(xs[rh * 4 + r][i], wv, acc[r]);
    }
    #pragma unroll
    for (int r = 0; r < 4; ++r) h1s[rh * 4 + r][h] = fmaxf(acc[r], 0.f);
  }
  __syncthreads();

  // layer 2: 128 -> 32. thread (row = t>>5, c = t&31): one output each
  {
    const int row = t >> 5, c = t & 31;
    float a = b2[c];
    #pragma unroll 4
    for (int i = 0; i < 128; ++i)
      a = fmaf(h1s[row][i], W2[i * 32 + c], a);
    if (e == 2) wsf[WS_V + (size_t)(r0 + row) * 32 + c] = a;
    else        encs[row][c] = a;
  }

  // hk (e==0) / hq (e==1): 8 rows x 64 h. thread (h = t&63, rp = t>>6): 2 rows
  if (e != 2) {
    __syncthreads();
    const int h = t & 63, rp = t >> 6;
    float bias = (e == 0) ? ab1[h] : 0.f;
    float s0 = bias, s1 = bias;
    const float* aw = aW1 + (e ? 32 * 64 : 0);
    #pragma unroll 4
    for (int cc = 0; cc < 32; ++cc) {
      float wv = aw[cc * 64 + h];
      s0 = fmaf(encs[rp * 2 + 0][cc], wv, s0);
      s1 = fmaf(encs[rp * 2 + 1][cc], wv, s1);
    }
    float* dst = wsf + (e ? WS_HQ : WS_HK);
    dst[(size_t)(r0 + rp * 2 + 0) * 64 + h] = s0;
    dst[(size_t)(r0 + rp * 2 + 1) * 64 + h] = s1;
  }
}

// ---------------------------------------------------------------------------
// Kernel 2: attention scores + sigmoid gate + aggregation  (v3: h-split,
// unchanged from round 5)
// grid: b(4) x itile(128, 4 rows) x jquarter(4, 128 j's) = 2048 blocks x 256 thr
// ---------------------------------------------------------------------------
__global__ __launch_bounds__(256, 4) void k_att(
    const float* __restrict__ v_ws, const float* __restrict__ hk_ws,
    const float* __restrict__ hq_ws, const float* __restrict__ aW2,
    const float* __restrict__ ab2, float* __restrict__ aggh)
{
  const int t = threadIdx.x;
  const int bid = blockIdx.x;
  const int jq = bid & 3;
  const int it = (bid >> 2) & 127;
  const int b  = bid >> 9;
  const int i0 = it * 4;
  const int jbase = jq * 128;

  // phase1 identity
  const int q   = t & 3;
  const int jj1 = (t >> 2) & 15;
  const int ii1 = t >> 6;
  const int ig  = i0 + ii1;

  // phase2 identity
  const int dd  = t & 15;
  const int c2  = (t >> 4) & 1;
  const int jh  = (t >> 5) & 1;
  const int i2  = t >> 6;

  __shared__ float hqs[2][16][68];
  __shared__ float vs[2][16][36];
  __shared__ float ws_w[2][4][20];        // [col][ii][jj]

  // persistent registers: 16 hk values + 16 aw2 per col for this lane-quarter
  float hk16[16];
  {
    const float4* hkp = (const float4*)(hk_ws + ((size_t)b * NN + ig) * 64 + q * 16);
    #pragma unroll
    for (int m = 0; m < 4; ++m) {
      float4 f = hkp[m];
      hk16[4 * m] = f.x; hk16[4 * m + 1] = f.y;
      hk16[4 * m + 2] = f.z; hk16[4 * m + 3] = f.w;
    }
  }
  float aw0[16], aw1[16];
  {
    const float4* awp = (const float4*)(aW2 + q * 32);  // pairs (h,c0),(h,c1)
    #pragma unroll
    for (int k = 0; k < 8; ++k) {
      float4 f = awp[k];
      aw0[2 * k] = f.x;     aw1[2 * k] = f.y;
      aw0[2 * k + 1] = f.z; aw1[2 * k + 1] = f.w;
    }
  }
  const float sb0 = ab2[0], sb1 = ab2[1];

  float accx = 0.f, accy = 0.f;
  const bool vload = (t < 128);

  // prologue: stage tile 0 into buffer 0
  {
    float4 hq_r = *(const float4*)(hq_ws + ((size_t)b * NN + jbase + (t >> 4)) * 64 + (t & 15) * 4);
    *(float4*)(&hqs[0][t >> 4][(t & 15) * 4]) = hq_r;
    if (vload) {
      float4 v_r = *(const float4*)(v_ws + ((size_t)b * NN + jbase + (t >> 3)) * 32 + (t & 7) * 4);
      *(float4*)(&vs[0][t >> 3][(t & 7) * 4]) = v_r;
    }
  }
  __syncthreads();

  int p = 0;
  for (int jt = 0; jt < 8; ++jt) {
    const int j0 = jbase + jt * 16;

    // issue next-tile global loads early (hidden under phase1 compute)
    float4 hq_n, v_n;
    if (jt < 7) {
      const int j0n = j0 + 16;
      hq_n = *(const float4*)(hq_ws + ((size_t)b * NN + j0n + (t >> 4)) * 64 + (t & 15) * 4);
      if (vload)
        v_n = *(const float4*)(v_ws + ((size_t)b * NN + j0n + (t >> 3)) * 32 + (t & 7) * 4);
    }

    // phase 1: partial scores over this lane's 16 h's, both cols
    {
      float s0 = 0.f, s1 = 0.f;
      #pragma unroll
      for (int mc = 0; mc < 4; ++mc) {
        float4 hq4 = *(const float4*)(&hqs[p][jj1][q * 16 + mc * 4]);
        float z;
        z = fmaxf(hk16[4 * mc + 0] + hq4.x, 0.f);
        s0 = fmaf(z, aw0[4 * mc + 0], s0); s1 = fmaf(z, aw1[4 * mc + 0], s1);
        z = fmaxf(hk16[4 * mc + 1] + hq4.y, 0.f);
        s0 = fmaf(z, aw0[4 * mc + 1], s0); s1 = fmaf(z, aw1[4 * mc + 1], s1);
        z = fmaxf(hk16[4 * mc + 2] + hq4.z, 0.f);
        s0 = fmaf(z, aw0[4 * mc + 2], s0); s1 = fmaf(z, aw1[4 * mc + 2], s1);
        z = fmaxf(hk16[4 * mc + 3] + hq4.w, 0.f);
        s0 = fmaf(z, aw0[4 * mc + 3], s0); s1 = fmaf(z, aw1[4 * mc + 3], s1);
      }
      // combine the 4 lane-quarters (bits 0-1 of t)
      s0 += __shfl_xor(s0, 1); s0 += __shfl_xor(s0, 2);
      s1 += __shfl_xor(s1, 1); s1 += __shfl_xor(s1, 2);
      s0 += sb0; s1 += sb1;
      // lanes q0/q2 produce col0, q1/q3 col1; q0,q1 write
      float sel = (q & 1) ? s1 : s0;
      float w = 1.f / (1.f + __expf(-sel));
      if (ig == j0 + jj1) w = 0.f;        // sigmoid(s - 10000) == 0 in fp32
      if (q < 2) ws_w[q][ii1][jj1] = w;
    }
    __syncthreads();   // w ready; vs[p] already ready

    // phase 2: agg partial for (i2, d=2dd..2dd+1, col c2, j-half jh)
    {
      float4 w4a = *(const float4*)(&ws_w[c2][i2][jh * 8]);
      float4 w4b = *(const float4*)(&ws_w[c2][i2][jh * 8 + 4]);
      const int jb = jh * 8;
      float2 vv;
      vv = *(const float2*)(&vs[p][jb + 0][2 * dd]);
      accx = fmaf(w4a.x, vv.x, accx); accy = fmaf(w4a.x, vv.y, accy);
      vv = *(const float2*)(&vs[p][jb + 1][2 * dd]);
      accx = fmaf(w4a.y, vv.x, accx); accy = fmaf(w4a.y, vv.y, accy);
      vv = *(const float2*)(&vs[p][jb + 2][2 * dd]);
      accx = fmaf(w4a.z, vv.x, accx); accy = fmaf(w4a.z, vv.y, accy);
      vv = *(const float2*)(&vs[p][jb + 3][2 * dd]);
      accx = fmaf(w4a.w, vv.x, accx); accy = fmaf(w4a.w, vv.y, accy);
      vv = *(const float2*)(&vs[p][jb + 4][2 * dd]);
      accx = fmaf(w4b.x, vv.x, accx); accy = fmaf(w4b.x, vv.y, accy);
      vv = *(const float2*)(&vs[p][jb + 5][2 * dd]);
      accx = fmaf(w4b.y, vv.x, accx); accy = fmaf(w4b.y, vv.y, accy);
      vv = *(const float2*)(&vs[p][jb + 6][2 * dd]);
      accx = fmaf(w4b.z, vv.x, accx); accy = fmaf(w4b.z, vv.y, accy);
      vv = *(const float2*)(&vs[p][jb + 7][2 * dd]);
      accx = fmaf(w4b.w, vv.x, accx); accy = fmaf(w4b.w, vv.y, accy);
    }

    // stage next tile into the other buffer (no conflict with phase2 reads)
    if (jt < 7) {
      *(float4*)(&hqs[p ^ 1][t >> 4][(t & 15) * 4]) = hq_n;
      if (vload) *(float4*)(&vs[p ^ 1][t >> 3][(t & 7) * 4]) = v_n;
    }
    __syncthreads();   // next buffer staged; ws_w free for next phase1
    p ^= 1;
  }

  // combine j-halves (bit 5 of t) and store
  accx += __shfl_xor(accx, 32);
  accy += __shfl_xor(accy, 32);
  if (jh == 0) {
    const size_t row = (size_t)b * NN + i0 + i2;
    float2 o; o.x = accx; o.y = accy;
    *(float2*)(&aggh[((size_t)(c2 * 4 + jq) * 2048 + row) * 32 + 2 * dd]) = o;
  }
}

// ---------------------------------------------------------------------------
// Kernel 3 (v2): decoders + heads. grid = rowpair(1024) x half(2) = 2048
// blocks x 256 thr = 8 blocks/CU = 32 waves/CU. 2 rows per block.
// ---------------------------------------------------------------------------
__global__ __launch_bounds__(256) void k_dec(
    const float* __restrict__ v_ws, const float* __restrict__ aggh,
    const float* __restrict__ dxW1, const float* __restrict__ dxb1,
    const float* __restrict__ dxW2, const float* __restrict__ dxb2,
    const float* __restrict__ dyW1, const float* __restrict__ dyb1,
    const float* __restrict__ dyW2, const float* __restrict__ dyb2,
    const float* __restrict__ mxW, const float* __restrict__ mxb,
    const float* __restrict__ sxW, const float* __restrict__ sxb,
    const float* __restrict__ myW, const float* __restrict__ myb,
    const float* __restrict__ syW, const float* __restrict__ syb,
    float* __restrict__ out)
{
  const int t = threadIdx.x;
  const int bid = blockIdx.x;
  const int half = bid & 1;               // 0: x-decoder (col0), 1: y-decoder
  const int r0 = (bid >> 1) * 2;          // 2 rows per block

  __shared__ float ccs[2][64];
  __shared__ float h1s[2][132];
  __shared__ float dds[2][64];

  if (t < 128) {                           // stage concat(v, agg) for 2 rows
    const float* aggp = aggh + (size_t)half * 4 * 65536;
    int r = t >> 6, i = t & 63;
    size_t row = (size_t)(r0 + r);
    float val;
    if (i < 32) {
      val = v_ws[row * 32 + i];
    } else {
      int o = i - 32;
      val = aggp[row * 32 + o] + aggp[65536 + row * 32 + o]
          + aggp[131072 + row * 32 + o] + aggp[196608 + row * 32 + o];
    }
    ccs[r][i] = val;
  }
  __syncthreads();

  const float* W1 = half ? dyW1 : dxW1;
  const float* b1 = half ? dyb1 : dxb1;
  const float* W2 = half ? dyW2 : dxW2;
  const float* b2 = half ? dyb2 : dxb2;

  // layer 1: 64 -> 128. thread (h = t&127, r = t>>7): one output each
  {
    const int h = t & 127, r = t >> 7;
    float acc = b1[h];
    #pragma unroll 4
    for (int i = 0; i < 64; ++i)
      acc = fmaf(ccs[r][i], W1[i * 128 + h], acc);
    h1s[r][h] = fmaxf(acc, 0.f);
  }
  __syncthreads();

  // layer 2: 128 -> 64. threads 0-127: (r = t>>6, c = t&63)
  if (t < 128) {
    const int r = t >> 6, c = t & 63;
    float a = b2[c];
    #pragma unroll 4
    for (int i = 0; i < 128; ++i)
      a = fmaf(h1s[r][i], W2[i * 64 + c], a);
    dds[r][c] = a;
  }
  __syncthreads();

  // heads: wave 0 -> row 0, wave 1 -> row 1 (waves 2,3 idle)
  {
    const int w = t >> 6, lane = t & 63;
    if (w < 2) {
      const float* mW = half ? myW : mxW;
      const float* sW = half ? syW : sxW;
      const float* mb = half ? myb : mxb;
      const float* sb = half ? syb : sxb;
      float dval = dds[w][lane];
      float pm = dval * mW[lane], ps = dval * sW[lane];
      #pragma unroll
      for (int msk = 32; msk >= 1; msk >>= 1) {
        pm += __shfl_xor(pm, msk);
        ps += __shfl_xor(ps, msk);
      }
      if (lane == 0) {
        float mu = pm + mb[0];
        float z = ps + sb[0];
        float sp = (z > 20.f) ? z : log1pf(__expf(z));
        out[half * 4096 + (r0 + w)] = mu;             // mu
        out[half * 4096 + 2048 + (r0 + w)] = sp;      // sig
      }
    }
  }
}

// ---------------------------------------------------------------------------
extern "C" void kernel_launch(void* const* d_in, const int* in_sizes, int n_in,
                              void* d_out, int out_size, void* d_ws, size_t ws_size,
                              hipStream_t stream) {
  (void)in_sizes; (void)n_in; (void)out_size; (void)ws_size;
  const float* x   = (const float*)d_in[0];
  const float* kW1 = (const float*)d_in[1];  const float* kb1 = (const float*)d_in[2];
  const float* kW2 = (const float*)d_in[3];  const float* kb2 = (const float*)d_in[4];
  const float* qW1 = (const float*)d_in[5];  const float* qb1 = (const float*)d_in[6];
  const float* qW2 = (const float*)d_in[7];  const float* qb2 = (const float*)d_in[8];
  const float* vW1 = (const float*)d_in[9];  const float* vb1 = (const float*)d_in[10];
  const float* vW2 = (const float*)d_in[11]; const float* vb2 = (const float*)d_in[12];
  const float* aW1 = (const float*)d_in[13]; const float* ab1 = (const float*)d_in[14];
  const float* aW2 = (const float*)d_in[15]; const float* ab2 = (const float*)d_in[16];
  const float* dxW1 = (const float*)d_in[17]; const float* dxb1 = (const float*)d_in[18];
  const float* dxW2 = (const float*)d_in[19]; const float* dxb2 = (const float*)d_in[20];
  const float* dyW1 = (const float*)d_in[21]; const float* dyb1 = (const float*)d_in[22];
  const float* dyW2 = (const float*)d_in[23]; const float* dyb2 = (const float*)d_in[24];
  const float* mxW = (const float*)d_in[25]; const float* mxb = (const float*)d_in[26];
  const float* sxW = (const float*)d_in[27]; const float* sxb = (const float*)d_in[28];
  const float* myW = (const float*)d_in[29]; const float* myb = (const float*)d_in[30];
  const float* syW = (const float*)d_in[31]; const float* syb = (const float*)d_in[32];

  float* wsf = (float*)d_ws;
  float* out = (float*)d_out;

  hipLaunchKernelGGL(k_enc, dim3(768), dim3(256), 0, stream,
                     x, kW1, kb1, kW2, kb2, qW1, qb1, qW2, qb2, vW1, vb1, vW2, vb2,
                     aW1, ab1, wsf);
  hipLaunchKernelGGL(k_att, dim3(2048), dim3(256), 0, stream,
                     wsf + WS_V, wsf + WS_HK, wsf + WS_HQ, aW2, ab2,
                     wsf + WS_AGG);
  hipLaunchKernelGGL(k_dec, dim3(2048), dim3(256), 0, stream,
                     wsf + WS_V, wsf + WS_AGG,
                     dxW1, dxb1, dxW2, dxb2, dyW1, dyb1, dyW2, dyb2,
                     mxW, mxb, sxW, sxb, myW, myb, syW, syb, out);
}

// Round 11
// 174.210 us; speedup vs baseline: 1.8405x; 1.0043x over previous
//
#include <hip/hip_runtime.h>
#include <hip/hip_bf16.h>

// Problem constants
#define BB 4
#define NN 512
// total rows = B*N = 2048

// workspace layout (float offsets)
#define WS_V    0         // [2048*32]
#define WS_HK   65536     // [2048*64]  (k@aW1[:32] + ab1)
#define WS_HQ   196608    // [2048*64]  (q@aW1[32:])
#define WS_AGG  327680    // [2 col][2 jq][2048][32] = 262144 floats

// ---------------------------------------------------------------------------
// Kernel 1 (v2): one encoder per block. grid = e(3) x rowtile(256, 8 rows),
// 256 threads. hk folded into e==0 blocks, hq into e==1 blocks. (unchanged)
// ---------------------------------------------------------------------------
__global__ __launch_bounds__(256) void k_enc(
    const float* __restrict__ x,
    const float* __restrict__ kW1, const float* __restrict__ kb1,
    const float* __restrict__ kW2, const float* __restrict__ kb2,
    const float* __restrict__ qW1, const float* __restrict__ qb1,
    const float* __restrict__ qW2, const float* __restrict__ qb2,
    const float* __restrict__ vW1, const float* __restrict__ vb1,
    const float* __restrict__ vW2, const float* __restrict__ vb2,
    const float* __restrict__ aW1, const float* __restrict__ ab1,
    float* __restrict__ wsf)
{
  const int t = threadIdx.x;
  const int bid = blockIdx.x;
  const int e  = bid >> 8;                // 0=k, 1=q, 2=v
  const int r0 = (bid & 255) * 8;         // global row base

  __shared__ float xs[8][64];
  __shared__ float h1s[8][132];           // padded
  __shared__ float encs[8][33];           // this encoder's 8x32 output

  const float* W1 = (e == 0) ? kW1 : (e == 1) ? qW1 : vW1;
  const float* b1 = (e == 0) ? kb1 : (e == 1) ? qb1 : vb1;
  const float* W2 = (e == 0) ? kW2 : (e == 1) ? qW2 : vW2;
  const float* b2 = (e == 0) ? kb2 : (e == 1) ? qb2 : vb2;

  {                                        // stage x: 512 floats, float2 each
    float2 f = ((const float2*)x)[(size_t)r0 * 32 + t];
    int m = t * 2;
    xs[m >> 6][m & 63] = f.x;
    xs[(m + 1) >> 6][(m + 1) & 63] = f.y;
  }
  __syncthreads();

  // layer 1: 64 -> 128. thread (h = t&127, rh = t>>7): 4 rows each
  {
    const int h = t & 127, rh = t >> 7;
    float acc[4];
    float bb = b1[h];
    #pragma unroll
    for (int r = 0; r < 4; ++r) acc[r] = bb;
    #pragma unroll 4
    for (int i = 0; i < 64; ++i) {
      float wv = W1[i * 128 + h];
      #pragma unroll
      for (int r = 0; r < 4; ++r) acc[r] = fmaf(xs[rh * 4 + r][i], wv, acc[r]);
    }
    #pragma unroll
    for (int r = 0; r < 4; ++r) h1s[rh * 4 + r][h] = fmaxf(acc[r], 0.f);
  }
  __syncthreads();

  // layer 2: 128 -> 32. thread (row = t>>5, c = t&31): one output each
  {
    const int row = t >> 5, c = t & 31;
    float a = b2[c];
    #pragma unroll 4
    for (int i = 0; i < 128; ++i)
      a = fmaf(h1s[row][i], W2[i * 32 + c], a);
    if (e == 2) wsf[WS_V + (size_t)(r0 + row) * 32 + c] = a;
    else        encs[row][c] = a;
  }

  // hk (e==0) / hq (e==1): 8 rows x 64 h. thread (h = t&63, rp = t>>6): 2 rows
  if (e != 2) {
    __syncthreads();
    const int h = t & 63, rp = t >> 6;
    float bias = (e == 0) ? ab1[h] : 0.f;
    float s0 = bias, s1 = bias;
    const float* aw = aW1 + (e ? 32 * 64 : 0);
    #pragma unroll 4
    for (int cc = 0; cc < 32; ++cc) {
      float wv = aw[cc * 64 + h];
      s0 = fmaf(encs[rp * 2 + 0][cc], wv, s0);
      s1 = fmaf(encs[rp * 2 + 1][cc], wv, s1);
    }
    float* dst = wsf + (e ? WS_HQ : WS_HK);
    dst[(size_t)(r0 + rp * 2 + 0) * 64 + h] = s0;
    dst[(size_t)(r0 + rp * 2 + 1) * 64 + h] = s1;
  }
}

// ---------------------------------------------------------------------------
// Kernel 2 (v4): 32-j tiles (half the barriers), jq=2 halves.
// grid: b(4) x itile(128, 4 rows) x jhalf(2, 256 j's) = 1024 blocks x 256 thr
// phase1: t = ii*64 + jj0*4 + q ; two slots jj = jj0, jj0+16 per thread.
//         lane-quarter q owns h in [q*16, q*16+16); shfl-combine over q.
// phase2: t = i2*64 + jh*32 + c2*16 + dd -> agg[i0+i2][2dd..2dd+1], col c2,
//         16-row half jh of the 32-row tile; shfl-combine over jh.
// ---------------------------------------------------------------------------
__global__ __launch_bounds__(256, 4) void k_att(
    const float* __restrict__ v_ws, const float* __restrict__ hk_ws,
    const float* __restrict__ hq_ws, const float* __restrict__ aW2,
    const float* __restrict__ ab2, float* __restrict__ aggh)
{
  const int t = threadIdx.x;
  const int bid = blockIdx.x;
  const int jq = bid & 1;
  const int it = (bid >> 1) & 127;
  const int b  = bid >> 8;
  const int i0 = it * 4;
  const int jbase = jq * 256;

  // phase1 identity
  const int q   = t & 3;
  const int jj0 = (t >> 2) & 15;
  const int ii1 = t >> 6;
  const int ig  = i0 + ii1;

  // phase2 identity
  const int dd  = t & 15;
  const int c2  = (t >> 4) & 1;
  const int jh  = (t >> 5) & 1;
  const int i2  = t >> 6;

  __shared__ float hqs[2][32][68];        // 2-way bank aliasing only
  __shared__ float vs[2][32][36];
  __shared__ float ws_w[2][4][36];        // [col][ii][jj 0..31]

  // persistent registers: 16 hk values + 16 aw2 per col for this lane-quarter
  float hk16[16];
  {
    const float4* hkp = (const float4*)(hk_ws + ((size_t)b * NN + ig) * 64 + q * 16);
    #pragma unroll
    for (int m = 0; m < 4; ++m) {
      float4 f = hkp[m];
      hk16[4 * m] = f.x; hk16[4 * m + 1] = f.y;
      hk16[4 * m + 2] = f.z; hk16[4 * m + 3] = f.w;
    }
  }
  float aw0[16], aw1[16];
  {
    const float4* awp = (const float4*)(aW2 + q * 32);  // pairs (h,c0),(h,c1)
    #pragma unroll
    for (int k = 0; k < 8; ++k) {
      float4 f = awp[k];
      aw0[2 * k] = f.x;     aw1[2 * k] = f.y;
      aw0[2 * k + 1] = f.z; aw1[2 * k + 1] = f.w;
    }
  }
  const float sb0 = ab2[0], sb1 = ab2[1];

  float accx = 0.f, accy = 0.f;

  // staging maps: hq tile (32r x 64): 512 float4, 2/thread; v tile: 256, 1/thread
  const int hr0 = t >> 4, hc0 = (t & 15) * 4;    // rows 0-15 slot
  const int vr0 = t >> 3, vc0 = (t & 7) * 4;

  // prologue: stage tile 0 into buffer 0
  {
    float4 a = *(const float4*)(hq_ws + ((size_t)b * NN + jbase + hr0) * 64 + hc0);
    float4 c = *(const float4*)(hq_ws + ((size_t)b * NN + jbase + 16 + hr0) * 64 + hc0);
    float4 v = *(const float4*)(v_ws + ((size_t)b * NN + jbase + vr0) * 32 + vc0);
    *(float4*)(&hqs[0][hr0][hc0]) = a;
    *(float4*)(&hqs[0][16 + hr0][hc0]) = c;
    *(float4*)(&vs[0][vr0][vc0]) = v;
  }
  __syncthreads();

  int p = 0;
  for (int jt = 0; jt < 8; ++jt) {
    const int j0 = jbase + jt * 32;

    // issue next-tile global loads early (hidden under phase1 compute)
    float4 hq_n0, hq_n1, v_n;
    if (jt < 7) {
      const int j0n = j0 + 32;
      hq_n0 = *(const float4*)(hq_ws + ((size_t)b * NN + j0n + hr0) * 64 + hc0);
      hq_n1 = *(const float4*)(hq_ws + ((size_t)b * NN + j0n + 16 + hr0) * 64 + hc0);
      v_n   = *(const float4*)(v_ws + ((size_t)b * NN + j0n + vr0) * 32 + vc0);
    }

    // phase 1: two score slots (jj0, jj0+16), both cols, h-split over q
    #pragma unroll
    for (int sub = 0; sub < 2; ++sub) {
      const int jj = jj0 + sub * 16;
      float s0 = 0.f, s1 = 0.f;
      #pragma unroll
      for (int mc = 0; mc < 4; ++mc) {
        float4 hq4 = *(const float4*)(&hqs[p][jj][q * 16 + mc * 4]);
        float z;
        z = fmaxf(hk16[4 * mc + 0] + hq4.x, 0.f);
        s0 = fmaf(z, aw0[4 * mc + 0], s0); s1 = fmaf(z, aw1[4 * mc + 0], s1);
        z = fmaxf(hk16[4 * mc + 1] + hq4.y, 0.f);
        s0 = fmaf(z, aw0[4 * mc + 1], s0); s1 = fmaf(z, aw1[4 * mc + 1], s1);
        z = fmaxf(hk16[4 * mc + 2] + hq4.z, 0.f);
        s0 = fmaf(z, aw0[4 * mc + 2], s0); s1 = fmaf(z, aw1[4 * mc + 2], s1);
        z = fmaxf(hk16[4 * mc + 3] + hq4.w, 0.f);
        s0 = fmaf(z, aw0[4 * mc + 3], s0); s1 = fmaf(z, aw1[4 * mc + 3], s1);
      }
      s0 += __shfl_xor(s0, 1); s0 += __shfl_xor(s0, 2);
      s1 += __shfl_xor(s1, 1); s1 += __shfl_xor(s1, 2);
      s0 += sb0; s1 += sb1;
      float sel = (q & 1) ? s1 : s0;
      float w = 1.f / (1.f + __expf(-sel));
      if (ig == j0 + jj) w = 0.f;         // sigmoid(s - 10000) == 0 in fp32
      if (q < 2) ws_w[q][ii1][jj] = w;
    }
    __syncthreads();   // w ready; vs[p] staged last iteration

    // phase 2: agg partial over this thread's 16-row half
    {
      const int jb = jh * 16;
      float4 wq[4];
      #pragma unroll
      for (int k = 0; k < 4; ++k)
        wq[k] = *(const float4*)(&ws_w[c2][i2][jb + 4 * k]);
      #pragma unroll
      for (int k = 0; k < 4; ++k) {
        float2 vv;
        vv = *(const float2*)(&vs[p][jb + 4 * k + 0][2 * dd]);
        accx = fmaf(wq[k].x, vv.x, accx); accy = fmaf(wq[k].x, vv.y, accy);
        vv = *(const float2*)(&vs[p][jb + 4 * k + 1][2 * dd]);
        accx = fmaf(wq[k].y, vv.x, accx); accy = fmaf(wq[k].y, vv.y, accy);
        vv = *(const float2*)(&vs[p][jb + 4 * k + 2][2 * dd]);
        accx = fmaf(wq[k].z, vv.x, accx); accy = fmaf(wq[k].z, vv.y, accy);
        vv = *(const float2*)(&vs[p][jb + 4 * k + 3][2 * dd]);
        accx = fmaf(wq[k].w, vv.x, accx); accy = fmaf(wq[k].w, vv.y, accy);
      }
    }

    // stage next tile into the other buffer (no conflict with phase2 reads)
    if (jt < 7) {
      *(float4*)(&hqs[p ^ 1][hr0][hc0]) = hq_n0;
      *(float4*)(&hqs[p ^ 1][16 + hr0][hc0]) = hq_n1;
      *(float4*)(&vs[p ^ 1][vr0][vc0]) = v_n;
    }
    __syncthreads();   // next buffer staged; ws_w free for next phase1
    p ^= 1;
  }

  // combine 16-row halves (bit 5 of t) and store
  accx += __shfl_xor(accx, 32);
  accy += __shfl_xor(accy, 32);
  if (jh == 0) {
    const size_t row = (size_t)b * NN + i0 + i2;
    float2 o; o.x = accx; o.y = accy;
    *(float2*)(&aggh[((size_t)(c2 * 2 + jq) * 2048 + row) * 32 + 2 * dd]) = o;
  }
}

// ---------------------------------------------------------------------------
// Kernel 3 (v3): decoders + heads. grid = rowquad(512) x half(2) = 1024
// blocks x 256 thr, 4 rows per block, all threads active every phase.
// ---------------------------------------------------------------------------
__global__ __launch_bounds__(256) void k_dec(
    const float* __restrict__ v_ws, const float* __restrict__ aggh,
    const float* __restrict__ dxW1, const float* __restrict__ dxb1,
    const float* __restrict__ dxW2, const float* __restrict__ dxb2,
    const float* __restrict__ dyW1, const float* __restrict__ dyb1,
    const float* __restrict__ dyW2, const float* __restrict__ dyb2,
    const float* __restrict__ mxW, const float* __restrict__ mxb,
    const float* __restrict__ sxW, const float* __restrict__ sxb,
    const float* __restrict__ myW, const float* __restrict__ myb,
    const float* __restrict__ syW, const float* __restrict__ syb,
    float* __restrict__ out)
{
  const int t = threadIdx.x;
  const int bid = blockIdx.x;
  const int half = bid & 1;               // 0: x-decoder (col0), 1: y-decoder
  const int r0 = (bid >> 1) * 4;          // 4 rows per block

  __shared__ float ccs[4][64];
  __shared__ float h1s[4][132];
  __shared__ float dds[4][64];

  {                                        // stage concat(v, agg) for 4 rows
    const float* aggp = aggh + (size_t)half * 2 * 65536;   // 2 jq partials
    const int r = t >> 6, i = t & 63;
    const size_t row = (size_t)(r0 + r);
    float val;
    if (i < 32) {
      val = v_ws[row * 32 + i];
    } else {
      const int o = i - 32;
      val = aggp[row * 32 + o] + aggp[65536 + row * 32 + o];
    }
    ccs[r][i] = val;
  }
  __syncthreads();

  const float* W1 = half ? dyW1 : dxW1;
  const float* b1 = half ? dyb1 : dxb1;
  const float* W2 = half ? dyW2 : dxW2;
  const float* b2 = half ? dyb2 : dxb2;

  // layer 1: 64 -> 128. thread (h = t&127, rh = t>>7): rows 2rh, 2rh+1
  {
    const int h = t & 127, rh = t >> 7;
    float a0 = b1[h], a1 = a0;
    #pragma unroll 4
    for (int i = 0; i < 64; ++i) {
      float wv = W1[i * 128 + h];
      a0 = fmaf(ccs[2 * rh + 0][i], wv, a0);
      a1 = fmaf(ccs[2 * rh + 1][i], wv, a1);
    }
    h1s[2 * rh + 0][h] = fmaxf(a0, 0.f);
    h1s[2 * rh + 1][h] = fmaxf(a1, 0.f);
  }
  __syncthreads();

  // layer 2: 128 -> 64. thread (r = t>>6, c = t&63): one output each
  {
    const int r = t >> 6, c = t & 63;
    float a = b2[c];
    #pragma unroll 4
    for (int i = 0; i < 128; ++i)
      a = fmaf(h1s[r][i], W2[i * 64 + c], a);
    dds[r][c] = a;
  }
  __syncthreads();

  // heads: wave w (0..3) -> row w
  {
    const int w = t >> 6, lane = t & 63;
    const float* mW = half ? myW : mxW;
    const float* sW = half ? syW : sxW;
    const float* mb = half ? myb : mxb;
    const float* sb = half ? syb : sxb;
    float dval = dds[w][lane];
    float pm = dval * mW[lane], ps = dval * sW[lane];
    #pragma unroll
    for (int msk = 32; msk >= 1; msk >>= 1) {
      pm += __shfl_xor(pm, msk);
      ps += __shfl_xor(ps, msk);
    }
    if (lane == 0) {
      float mu = pm + mb[0];
      float z = ps + sb[0];
      float sp = (z > 20.f) ? z : log1pf(__expf(z));
      out[half * 4096 + (r0 + w)] = mu;               // mu
      out[half * 4096 + 2048 + (r0 + w)] = sp;        // sig
    }
  }
}

// ---------------------------------------------------------------------------
extern "C" void kernel_launch(void* const* d_in, const int* in_sizes, int n_in,
                              void* d_out, int out_size, void* d_ws, size_t ws_size,
                              hipStream_t stream) {
  (void)in_sizes; (void)n_in; (void)out_size; (void)ws_size;
  const float* x   = (const float*)d_in[0];
  const float* kW1 = (const float*)d_in[1];  const float* kb1 = (const float*)d_in[2];
  const float* kW2 = (const float*)d_in[3];  const float* kb2 = (const float*)d_in[4];
  const float* qW1 = (const float*)d_in[5];  const float* qb1 = (const float*)d_in[6];
  const float* qW2 = (const float*)d_in[7];  const float* qb2 = (const float*)d_in[8];
  const float* vW1 = (const float*)d_in[9];  const float* vb1 = (const float*)d_in[10];
  const float* vW2 = (const float*)d_in[11]; const float* vb2 = (const float*)d_in[12];
  const float* aW1 = (const float*)d_in[13]; const float* ab1 = (const float*)d_in[14];
  const float* aW2 = (const float*)d_in[15]; const float* ab2 = (const float*)d_in[16];
  const float* dxW1 = (const float*)d_in[17]; const float* dxb1 = (const float*)d_in[18];
  const float* dxW2 = (const float*)d_in[19]; const float* dxb2 = (const float*)d_in[20];
  const float* dyW1 = (const float*)d_in[21]; const float* dyb1 = (const float*)d_in[22];
  const float* dyW2 = (const float*)d_in[23]; const float* dyb2 = (const float*)d_in[24];
  const float* mxW = (const float*)d_in[25]; const float* mxb = (const float*)d_in[26];
  const float* sxW = (const float*)d_in[27]; const float* sxb = (const float*)d_in[28];
  const float* myW = (const float*)d_in[29]; const float* myb = (const float*)d_in[30];
  const float* syW = (const float*)d_in[31]; const float* syb = (const float*)d_in[32];

  float* wsf = (float*)d_ws;
  float* out = (float*)d_out;

  hipLaunchKernelGGL(k_enc, dim3(768), dim3(256), 0, stream,
                     x, kW1, kb1, kW2, kb2, qW1, qb1, qW2, qb2, vW1, vb1, vW2, vb2,
                     aW1, ab1, wsf);
  hipLaunchKernelGGL(k_att, dim3(1024), dim3(256), 0, stream,
                     wsf + WS_V, wsf + WS_HK, wsf + WS_HQ, aW2, ab2,
                     wsf + WS_AGG);
  hipLaunchKernelGGL(k_dec, dim3(1024), dim3(256), 0, stream,
                     wsf + WS_V, wsf + WS_AGG,
                     dxW1, dxb1, dxW2, dxb2, dyW1, dyb1, dyW2, dyb2,
                     mxW, mxb, sxW, sxb, myW, myb, syW, syb, out);
}